// Round 15
// baseline (464.728 us; speedup 1.0000x reference)
//
#include <hip/hip_runtime.h>

#define DI __device__ __forceinline__

// Problem constants (B,C,T,F)=(2,256,1024,64), N=4, HID=64
static constexpr int B_ = 2;
static constexpr int C_ = 256;
static constexpr int T_ = 1024;
static constexpr int F_ = 64;
static constexpr int M_ = 8;      // N_*B_
static constexpr int E_ = 4096;   // HID*F = (C/N)*F
static constexpr float SCALE_ = 1.0f / 64.0f;   // 1/sqrt(4096)

typedef __attribute__((ext_vector_type(8))) short bf16x8;
typedef __attribute__((ext_vector_type(4))) float f32x4;

DI unsigned short bf16_rne(float f) {
    unsigned int u = __float_as_uint(f);
    return (unsigned short)((u + 0x7FFFu + ((u >> 16) & 1u)) >> 16);
}
DI float bf2f(unsigned short h) { return __uint_as_float(((unsigned int)h) << 16); }
DI ushort4 pack4(float a, float b, float c, float d) {
    return make_ushort4(bf16_rne(a), bf16_rne(b), bf16_rne(c), bf16_rne(d));
}
DI float4 up4(ushort4 u) {
    return make_float4(bf2f(u.x), bf2f(u.y), bf2f(u.z), bf2f(u.w));
}

// async global->LDS, 16B per lane; LDS dest = wave-uniform base + lane*16
DI void gload_lds16(const unsigned short* g, unsigned short* l) {
    __builtin_amdgcn_global_load_lds(
        (const __attribute__((address_space(1))) unsigned int*)g,
        (__attribute__((address_space(3))) unsigned int*)l, 16, 0, 0);
}

DI void mfma16(f32x4& acc, bf16x8 a, bf16x8 b) {
    asm("v_mfma_f32_16x16x32_bf16 %0, %1, %2, %0" : "+v"(acc) : "v"(a), "v"(b));
}

// ---------------------------------------------------------------------------
// K0: convert Wq|Wk|Wv -> Wall bf16 [768][256], Wp -> Wpb bf16 [256][256],
//     bias_all[768] = bq|bk|bv.
// ---------------------------------------------------------------------------
__global__ __launch_bounds__(256) void wconv_kernel(
    const float* __restrict__ Wq, const float* __restrict__ Wk,
    const float* __restrict__ Wv, const float* __restrict__ Wp,
    const float* __restrict__ bq, const float* __restrict__ bk,
    const float* __restrict__ bv,
    unsigned short* __restrict__ Wall, unsigned short* __restrict__ Wpb,
    float* __restrict__ bias_all)
{
    const int tid = (int)threadIdx.x;
    const int bid = (int)blockIdx.x;
    if (bid < 192) {
        const int idx = (bid * 256 + tid) * 4;
        const int proj = idx >> 16, rem = idx & 65535;
        const float* src = proj == 0 ? Wq : (proj == 1 ? Wk : Wv);
        float4 v = *(const float4*)(src + rem);
        *(ushort4*)(Wall + idx) = pack4(v.x, v.y, v.z, v.w);
        const int gid = bid * 256 + tid;
        if (gid < 768) {
            float bb = gid < 256 ? bq[gid] : (gid < 512 ? bk[gid - 256] : bv[gid - 512]);
            bias_all[gid] = bb;
        }
    } else {
        const int idx = ((bid - 192) * 256 + tid) * 4;
        float4 v = *(const float4*)(Wp + idx);
        *(ushort4*)(Wpb + idx) = pack4(v.x, v.y, v.z, v.w);
    }
}

// ---------------------------------------------------------------------------
// K1: single-pass QKV projection (round-13, measured 140us)
// ---------------------------------------------------------------------------
__global__ __launch_bounds__(256) void qkv_one(
    const float* __restrict__ x, const unsigned short* __restrict__ Wall,
    const float* __restrict__ bias_all, unsigned short* __restrict__ outQ)
{
    const int wgid = (int)blockIdx.x;          // 0..1023
    const int b = wgid >> 9, tft = wgid & 511;
    const int tfbase = tft * 128;

    const int tid = (int)threadIdx.x;
    const int wid = tid >> 6, lane = tid & 63;
    const int wr = wid >> 1, wc = wid & 1;
    const int lo16 = lane & 15, hi4 = lane >> 4;

    __shared__ unsigned short As[4 * 128 * 64];   // 64 KB panel
    __shared__ unsigned short Bs[128 * 64];       // 16 KB

    {
        const int a = lane & 7, cg = lane >> 3;
        const int rowb = wid * 32 + a * 4;
        const float* xb = x + (size_t)b * (C_ * T_ * F_) + tfbase + rowb;
        for (int cb = 0; cb < 256; cb += 64) {
            const int c0 = cb + cg * 8;
            float4 v[8];
#pragma unroll
            for (int g = 0; g < 8; ++g)
                v[g] = *(const float4*)(xb + (size_t)(c0 + g) * 65536);
            const int kc = cb >> 6;
#pragma unroll
            for (int j = 0; j < 4; ++j) {
                const int row = rowb + j;
                const int col8 = cg ^ (row & 7);
                float e0 = (&v[0].x)[j], e1 = (&v[1].x)[j], e2 = (&v[2].x)[j], e3 = (&v[3].x)[j];
                float e4 = (&v[4].x)[j], e5 = (&v[5].x)[j], e6 = (&v[6].x)[j], e7 = (&v[7].x)[j];
                ushort4 p0 = pack4(e0, e1, e2, e3);
                ushort4 p1 = pack4(e4, e5, e6, e7);
                *(ushort4*)&As[kc * 8192 + row * 64 + col8 * 8]     = p0;
                *(ushort4*)&As[kc * 8192 + row * 64 + col8 * 8 + 4] = p1;
            }
        }
    }

    const int srow = lane >> 3;
    const int scol = ((lane & 7) ^ srow) * 8;
    const int tf0 = tfbase + wr * 64;

    const int krot = wgid & 3;
    int nrot = wgid % 6;

    __syncthreads();

    for (int ntl_i = 0; ntl_i < 6; ++ntl_i) {
        int ntl = ntl_i + nrot; if (ntl >= 6) ntl -= 6;
        const int nbase = ntl * 128;
        const unsigned short* brow = Wall + (size_t)nbase * 256;
        f32x4 acc[4][4] = {};

        for (int kc_i = 0; kc_i < 4; ++kc_i) {
            const int kc = (kc_i + krot) & 3;
#pragma unroll
            for (int i = 0; i < 4; ++i) {
                const int rb = wid * 32 + i * 8;
                gload_lds16(brow + (size_t)(rb + srow) * 256 + kc * 64 + scol,
                            &Bs[rb * 64]);
            }
            __syncthreads();
#pragma unroll
            for (int kk = 0; kk < 2; ++kk) {
                const int hc = (kk * 32 + hi4 * 8) ^ ((lane & 7) << 3);
                bf16x8 a[4], bb[4];
#pragma unroll
                for (int mi = 0; mi < 4; ++mi)
                    a[mi] = *(const bf16x8*)&As[kc * 8192 + (wr * 64 + mi * 16 + lo16) * 64 + hc];
#pragma unroll
                for (int nj = 0; nj < 4; ++nj)
                    bb[nj] = *(const bf16x8*)&Bs[(wc * 64 + nj * 16 + lo16) * 64 + hc];
#pragma unroll
                for (int mi = 0; mi < 4; ++mi)
#pragma unroll
                    for (int nj = 0; nj < 4; ++nj)
                        mfma16(acc[mi][nj], a[mi], bb[nj]);
            }
            __syncthreads();
        }

        asm volatile("s_nop 7\n\ts_nop 7" ::: "memory");
#pragma unroll
        for (int nj = 0; nj < 4; ++nj) {
            const int r_col = nbase + wc * 64 + nj * 16 + lo16;
            const int projl = r_col >> 8;
            const int rr = r_col & 255;
            const int mrow = (rr >> 6) * 2 + b;
            const int h = rr & 63;
            const float bv = bias_all[r_col];
            unsigned short* dst0 = outQ + (size_t)projl * 33554432
                                 + (size_t)mrow * (T_ * E_) + h * 64;
#pragma unroll
            for (int mi = 0; mi < 4; ++mi) {
                const int tf = tf0 + mi * 16 + hi4 * 4;
                const int t = tf >> 6, f = tf & 63;
                *(ushort4*)(dst0 + (size_t)t * E_ + f) =
                    pack4(acc[mi][nj][0] + bv, acc[mi][nj][1] + bv,
                          acc[mi][nj][2] + bv, acc[mi][nj][3] + bv);
            }
        }
        if (ntl_i < 5) __syncthreads();
    }
}

// ---------------------------------------------------------------------------
// K2: scores, MFMA NT GEMM, XCD-chunked 1-D grid (round-6 verified)
// ---------------------------------------------------------------------------
__global__ __launch_bounds__(256) void scores_mfma(
    const unsigned short* __restrict__ Q, const unsigned short* __restrict__ K,
    unsigned short* __restrict__ S)
{
    const int orig = (int)blockIdx.x;                     // 512 blocks
    const int wg = (orig & 7) * 64 + (orig >> 3);
    const int m = wg >> 6;
    const int rest = wg & 63;
    const int sbase = (rest & 7) * 128;
    const int tbase = (rest >> 3) * 128;
    const int tid = (int)threadIdx.x;
    const int wid = tid >> 6, lane = tid & 63;
    const int wr = wid >> 1, wc = wid & 1;
    const int lo16 = lane & 15, hi4 = lane >> 4;

    __shared__ unsigned short As[128 * 64];
    __shared__ unsigned short Bs[128 * 64];

    f32x4 acc[4][4] = {};

    const unsigned short* qrow = Q + ((size_t)m * T_ + tbase) * E_;
    const unsigned short* krow = K + ((size_t)m * T_ + sbase) * E_;

    const int srow = lane >> 3;
    const int scol = ((lane & 7) ^ srow) * 8;

    for (int eb = 0; eb < E_; eb += 64) {
#pragma unroll
        for (int i = 0; i < 4; ++i) {
            const int rb = wid * 32 + i * 8;
            gload_lds16(qrow + (size_t)(rb + srow) * E_ + eb + scol, &As[rb * 64]);
            gload_lds16(krow + (size_t)(rb + srow) * E_ + eb + scol, &Bs[rb * 64]);
        }
        __syncthreads();
#pragma unroll
        for (int kk = 0; kk < 2; ++kk) {
            const int hc = (kk * 32 + hi4 * 8) ^ ((lane & 7) << 3);
            bf16x8 a[4], bb[4];
#pragma unroll
            for (int mi = 0; mi < 4; ++mi)
                a[mi] = *(const bf16x8*)&As[(wr * 64 + mi * 16 + lo16) * 64 + hc];
#pragma unroll
            for (int nj = 0; nj < 4; ++nj)
                bb[nj] = *(const bf16x8*)&Bs[(wc * 64 + nj * 16 + lo16) * 64 + hc];
#pragma unroll
            for (int mi = 0; mi < 4; ++mi)
#pragma unroll
                for (int nj = 0; nj < 4; ++nj)
                    mfma16(acc[mi][nj], a[mi], bb[nj]);
        }
        __syncthreads();
    }

    asm volatile("s_nop 7\n\ts_nop 7" ::: "memory");
#pragma unroll
    for (int mi = 0; mi < 4; ++mi)
#pragma unroll
        for (int r = 0; r < 4; ++r) {
            int trow = tbase + wr * 64 + mi * 16 + hi4 * 4 + r;
            unsigned short* sp = S + ((size_t)m * T_ + trow) * T_ + sbase + wc * 64 + lo16;
#pragma unroll
            for (int nj = 0; nj < 4; ++nj)
                sp[nj * 16] = bf16_rne(acc[mi][nj][r] * SCALE_);
        }
}

// ---------------------------------------------------------------------------
// K3: row softmax, one row per wave (round-12 verified)
// ---------------------------------------------------------------------------
__global__ __launch_bounds__(256) void softmax_kernel(
    const unsigned short* __restrict__ S, unsigned short* __restrict__ A)
{
    const int tid = (int)threadIdx.x;
    const int wid = tid >> 6, lane = tid & 63;
    const size_t rowoff = ((size_t)blockIdx.x * 4 + wid) * 1024;   // 2048 blocks

    const size_t off = rowoff + lane * 16;
    bf16x8 u0 = *(const bf16x8*)(S + off);
    bf16x8 u1 = *(const bf16x8*)(S + off + 8);

    float v[16];
#pragma unroll
    for (int i = 0; i < 8; ++i) {
        v[i]     = bf2f((unsigned short)u0[i]);
        v[i + 8] = bf2f((unsigned short)u1[i]);
    }

    float mx = v[0];
#pragma unroll
    for (int i = 1; i < 16; ++i) mx = fmaxf(mx, v[i]);
#pragma unroll
    for (int off2 = 32; off2 > 0; off2 >>= 1) mx = fmaxf(mx, __shfl_xor(mx, off2));

    float sm = 0.f;
#pragma unroll
    for (int i = 0; i < 16; ++i) { v[i] = __expf(v[i] - mx); sm += v[i]; }
#pragma unroll
    for (int off2 = 32; off2 > 0; off2 >>= 1) sm += __shfl_xor(sm, off2);
    const float inv = 1.0f / sm;

    bf16x8 r0, r1;
#pragma unroll
    for (int i = 0; i < 8; ++i) {
        r0[i] = (short)bf16_rne(v[i] * inv);
        r1[i] = (short)bf16_rne(v[i + 8] * inv);
    }
    *(bf16x8*)(A + off)     = r0;
    *(bf16x8*)(A + off + 8) = r1;
}

// ---------------------------------------------------------------------------
// K4: PV fused with V-transpose staging (vt_kernel eliminated).
// 128x128 tile (round-6-verified pv_mfma structure); A staged via
// gload_lds16 from attn weights (s-contiguous); B staged DIRECTLY from
// V[m][s][d] with an in-register 4s x 8d transpose into the swizzled
// Bs layout (same pattern as outproj_fused's A-stage, round-13 verified).
// ---------------------------------------------------------------------------
__global__ __launch_bounds__(256) void pv_fused(
    const unsigned short* __restrict__ A, const unsigned short* __restrict__ V,
    unsigned short* __restrict__ G)
{
    const int orig = (int)blockIdx.x;                     // 2048 blocks
    const int wg = (orig & 7) * 256 + (orig >> 3);
    const int m = wg >> 8;
    const int rest = wg & 255;
    const int dbase = (rest & 31) * 128;
    const int tbase = (rest >> 5) * 128;
    const int nh = m >> 1, b = m & 1;
    const int tid = (int)threadIdx.x;
    const int wid = tid >> 6, lane = tid & 63;
    const int wr = wid >> 1, wc = wid & 1;
    const int lo16 = lane & 15, hi4 = lane >> 4;

    __shared__ unsigned short As[128 * 64];
    __shared__ unsigned short Bs[128 * 64];

    f32x4 acc[4][4] = {};

    const unsigned short* arow = A + ((size_t)m * T_ + tbase) * T_;

    const int srow = lane >> 3;
    const int scol = ((lane & 7) ^ srow) * 8;

    // lane roles for the B transpose-stage
    const int sa = tid >> 4;      // 0..15 -> s sub-rows sa*4 .. sa*4+3
    const int dg = tid & 15;      // 0..15 -> d rows dg*8 .. dg*8+7

    for (int sb = 0; sb < T_; sb += 64) {
        // stage A (attn weights, K-contiguous) via verified gload path
#pragma unroll
        for (int i = 0; i < 4; ++i) {
            const int rb = wid * 32 + i * 8;
            gload_lds16(arow + (size_t)(rb + srow) * T_ + sb + scol, &As[rb * 64]);
        }
        // stage B from V[m][s][d] with in-register transpose (rows = d)
        {
            const unsigned short* vsrc = V + ((size_t)m * T_ + sb + sa * 4) * E_
                                       + dbase + dg * 8;
            bf16x8 v0 = *(const bf16x8*)(vsrc);
            bf16x8 v1 = *(const bf16x8*)(vsrc + E_);
            bf16x8 v2 = *(const bf16x8*)(vsrc + 2 * E_);
            bf16x8 v3 = *(const bf16x8*)(vsrc + 3 * E_);
#pragma unroll
            for (int e = 0; e < 8; ++e) {
                const int r = dg * 8 + e;
                const int phys = r * 64 + ((((sa >> 1) ^ (r & 7)) << 3) + (sa & 1) * 4);
                ushort4 w = make_ushort4((unsigned short)v0[e], (unsigned short)v1[e],
                                         (unsigned short)v2[e], (unsigned short)v3[e]);
                *(ushort4*)&Bs[phys] = w;
            }
        }
        __syncthreads();
#pragma unroll
        for (int kk = 0; kk < 2; ++kk) {
            const int hc = (kk * 32 + hi4 * 8) ^ ((lane & 7) << 3);
            bf16x8 a[4], bb[4];
#pragma unroll
            for (int mi = 0; mi < 4; ++mi)
                a[mi] = *(const bf16x8*)&As[(wr * 64 + mi * 16 + lo16) * 64 + hc];
#pragma unroll
            for (int nj = 0; nj < 4; ++nj)
                bb[nj] = *(const bf16x8*)&Bs[(wc * 64 + nj * 16 + lo16) * 64 + hc];
#pragma unroll
            for (int mi = 0; mi < 4; ++mi)
#pragma unroll
                for (int nj = 0; nj < 4; ++nj)
                    mfma16(acc[mi][nj], a[mi], bb[nj]);
        }
        __syncthreads();
    }

    asm volatile("s_nop 7\n\ts_nop 7" ::: "memory");
    const int cb   = nh * 64 + (dbase >> 6) + wc;
    const int t2lo = (tbase >> 6) + wr;
#pragma unroll
    for (int mi = 0; mi < 4; ++mi) {
        const int tl = mi * 16 + hi4 * 4;
#pragma unroll
        for (int nj = 0; nj < 4; ++nj) {
            const int d63 = nj * 16 + lo16;
            size_t addr = (((size_t)(b * 256 + cb)) * 1024 + d63 * 16 + t2lo) * 64 + tl;
            *(ushort4*)&G[addr] = pack4(acc[mi][nj][0], acc[mi][nj][1],
                                        acc[mi][nj][2], acc[mi][nj][3]);
        }
    }
}

// ---------------------------------------------------------------------------
// K5: out projection FUSED with G transpose (round-13 verified)
// ---------------------------------------------------------------------------
__global__ __launch_bounds__(256) void outproj_fused(
    const unsigned short* __restrict__ G, const unsigned short* __restrict__ Wpb,
    const float* __restrict__ bp, const float* __restrict__ x,
    float* __restrict__ out)
{
    const int tfbase = blockIdx.x * 128;
    const int obase  = blockIdx.y * 128;
    const int b      = blockIdx.z;
    const int tid = (int)threadIdx.x;
    const int wid = tid >> 6, lane = tid & 63;
    const int wr = wid >> 1, wc = wid & 1;
    const int lo16 = lane & 15, hi4 = lane >> 4;

    __shared__ unsigned short As[128 * 64];
    __shared__ unsigned short Bs[128 * 64];

    f32x4 acc[4][4] = {};

    const unsigned short* brow = Wpb + (size_t)obase * 256;

    const int srow = lane >> 3;
    const int scol = ((lane & 7) ^ srow) * 8;

    const int cg = tid >> 4;
    const int ag = tid & 15;

    for (int cb = 0; cb < 256; cb += 64) {
#pragma unroll
        for (int i = 0; i < 4; ++i) {
            const int rb = wid * 32 + i * 8;
            gload_lds16(brow + (size_t)(rb + srow) * 256 + cb + scol, &Bs[rb * 64]);
        }
        {
            const unsigned short* gb = G + ((size_t)(b * 256 + cb + cg * 4)) * 65536
                                     + tfbase + ag * 8;
            bf16x8 vv0 = *(const bf16x8*)(gb);
            bf16x8 vv1 = *(const bf16x8*)(gb + 65536);
            bf16x8 vv2 = *(const bf16x8*)(gb + 2 * 65536);
            bf16x8 vv3 = *(const bf16x8*)(gb + 3 * 65536);
#pragma unroll
            for (int j = 0; j < 8; ++j) {
                const int row = ag * 8 + j;
                const int phys = row * 64 + ((((cg >> 1) ^ (row & 7)) << 3) + (cg & 1) * 4);
                ushort4 w = make_ushort4((unsigned short)vv0[j], (unsigned short)vv1[j],
                                         (unsigned short)vv2[j], (unsigned short)vv3[j]);
                *(ushort4*)&As[phys] = w;
            }
        }
        __syncthreads();
#pragma unroll
        for (int kk = 0; kk < 2; ++kk) {
            const int hc = (kk * 32 + hi4 * 8) ^ ((lane & 7) << 3);
            bf16x8 a[4], bb[4];
#pragma unroll
            for (int mi = 0; mi < 4; ++mi)
                a[mi] = *(const bf16x8*)&As[(wr * 64 + mi * 16 + lo16) * 64 + hc];
#pragma unroll
            for (int nj = 0; nj < 4; ++nj)
                bb[nj] = *(const bf16x8*)&Bs[(wc * 64 + nj * 16 + lo16) * 64 + hc];
#pragma unroll
            for (int mi = 0; mi < 4; ++mi)
#pragma unroll
                for (int nj = 0; nj < 4; ++nj)
                    mfma16(acc[mi][nj], a[mi], bb[nj]);
        }
        __syncthreads();
    }

    asm volatile("s_nop 7\n\ts_nop 7" ::: "memory");
#pragma unroll
    for (int nj = 0; nj < 4; ++nj) {
        const int o = obase + wc * 64 + nj * 16 + lo16;
        const float bias = bp[o];
        const size_t rowb = ((size_t)(b * 256 + o)) * 65536;
#pragma unroll
        for (int mi = 0; mi < 4; ++mi) {
            const int tf = tfbase + wr * 64 + mi * 16 + hi4 * 4;
            float4 xv = *(const float4*)(x + rowb + tf);
            float4 r = make_float4(acc[mi][nj][0] + bias + xv.x,
                                   acc[mi][nj][1] + bias + xv.y,
                                   acc[mi][nj][2] + bias + xv.z,
                                   acc[mi][nj][3] + bias + xv.w);
            *(float4*)(out + rowb + tf) = r;
        }
    }
}

// ---------------------------------------------------------------------------
extern "C" void kernel_launch(void* const* d_in, const int* in_sizes, int n_in,
                              void* d_out, int out_size, void* d_ws, size_t ws_size,
                              hipStream_t stream) {
    const float* x  = (const float*)d_in[0];
    const float* Wq = (const float*)d_in[1];
    const float* bq = (const float*)d_in[2];
    const float* Wk = (const float*)d_in[3];
    const float* bk = (const float*)d_in[4];
    const float* Wv = (const float*)d_in[5];
    const float* bv = (const float*)d_in[6];
    const float* Wp = (const float*)d_in[7];
    const float* bp = (const float*)d_in[8];
    float* out = (float*)d_out;

    // workspace layout (peak ~235.4 MB)
    char* ws = (char*)d_ws;
    unsigned short* Q    = (unsigned short*)(ws);                 // R0: Q -> G
    unsigned short* K    = (unsigned short*)(ws + 67108864);      // R1: K (dead after scores)
    unsigned short* V    = (unsigned short*)(ws + 134217728);     // R2: V
    unsigned short* S    = (unsigned short*)(ws + 201326592);     // 16 MB
    unsigned short* A    = (unsigned short*)(ws + 218103808);     // 16 MB
    unsigned short* Wall = (unsigned short*)(ws + 234881024);     // 393216 B
    float* bias_all      = (float*)(ws + 235274240);              // 3072 B
    unsigned short* Wpb  = (unsigned short*)(ws + 235277312);     // 131072 B
    unsigned short* G  = Q;    // written after scores (Q dead)

    wconv_kernel<<<256, 256, 0, stream>>>(Wq, Wk, Wv, Wp, bq, bk, bv, Wall, Wpb, bias_all);
    qkv_one<<<1024, 256, 0, stream>>>(x, Wall, bias_all, Q);      // Q,K,V in one pass
    scores_mfma<<<512, 256, 0, stream>>>(Q, K, S);
    softmax_kernel<<<2048, 256, 0, stream>>>(S, A);
    pv_fused<<<2048, 256, 0, stream>>>(A, V, G);
    outproj_fused<<<dim3(512, 2, 2), 256, 0, stream>>>(G, Wpb, bp, x, out);
}

// Round 16
// 394.614 us; speedup vs baseline: 1.1777x; 1.1777x over previous
//
#include <hip/hip_runtime.h>

#define DI __device__ __forceinline__

// Problem constants (B,C,T,F)=(2,256,1024,64), N=4, HID=64
static constexpr int B_ = 2;
static constexpr int C_ = 256;
static constexpr int T_ = 1024;
static constexpr int F_ = 64;
static constexpr int M_ = 8;      // N_*B_
static constexpr int E_ = 4096;   // HID*F = (C/N)*F
static constexpr float SCALE_ = 1.0f / 64.0f;   // 1/sqrt(4096)

typedef __attribute__((ext_vector_type(8))) short bf16x8;
typedef __attribute__((ext_vector_type(4))) float f32x4;

DI unsigned short bf16_rne(float f) {
    unsigned int u = __float_as_uint(f);
    return (unsigned short)((u + 0x7FFFu + ((u >> 16) & 1u)) >> 16);
}
DI float bf2f(unsigned short h) { return __uint_as_float(((unsigned int)h) << 16); }
DI ushort4 pack4(float a, float b, float c, float d) {
    return make_ushort4(bf16_rne(a), bf16_rne(b), bf16_rne(c), bf16_rne(d));
}
DI float4 up4(ushort4 u) {
    return make_float4(bf2f(u.x), bf2f(u.y), bf2f(u.z), bf2f(u.w));
}

// async global->LDS, 16B per lane; LDS dest = wave-uniform base + lane*16
DI void gload_lds16(const unsigned short* g, unsigned short* l) {
    __builtin_amdgcn_global_load_lds(
        (const __attribute__((address_space(1))) unsigned int*)g,
        (__attribute__((address_space(3))) unsigned int*)l, 16, 0, 0);
}

DI void mfma16(f32x4& acc, bf16x8 a, bf16x8 b) {
    asm("v_mfma_f32_16x16x32_bf16 %0, %1, %2, %0" : "+v"(acc) : "v"(a), "v"(b));
}

// ---------------------------------------------------------------------------
// K0: convert Wq|Wk|Wv -> Wall bf16 [768][256], Wp -> Wpb bf16 [256][256],
//     bias_all[768] = bq|bk|bv.
// ---------------------------------------------------------------------------
__global__ __launch_bounds__(256) void wconv_kernel(
    const float* __restrict__ Wq, const float* __restrict__ Wk,
    const float* __restrict__ Wv, const float* __restrict__ Wp,
    const float* __restrict__ bq, const float* __restrict__ bk,
    const float* __restrict__ bv,
    unsigned short* __restrict__ Wall, unsigned short* __restrict__ Wpb,
    float* __restrict__ bias_all)
{
    const int tid = (int)threadIdx.x;
    const int bid = (int)blockIdx.x;
    if (bid < 192) {
        const int idx = (bid * 256 + tid) * 4;
        const int proj = idx >> 16, rem = idx & 65535;
        const float* src = proj == 0 ? Wq : (proj == 1 ? Wk : Wv);
        float4 v = *(const float4*)(src + rem);
        *(ushort4*)(Wall + idx) = pack4(v.x, v.y, v.z, v.w);
        const int gid = bid * 256 + tid;
        if (gid < 768) {
            float bb = gid < 256 ? bq[gid] : (gid < 512 ? bk[gid - 256] : bv[gid - 512]);
            bias_all[gid] = bb;
        }
    } else {
        const int idx = ((bid - 192) * 256 + tid) * 4;
        float4 v = *(const float4*)(Wp + idx);
        *(ushort4*)(Wpb + idx) = pack4(v.x, v.y, v.z, v.w);
    }
}

// ---------------------------------------------------------------------------
// K1: single-pass QKV projection (round-13, measured 140us)
// ---------------------------------------------------------------------------
__global__ __launch_bounds__(256) void qkv_one(
    const float* __restrict__ x, const unsigned short* __restrict__ Wall,
    const float* __restrict__ bias_all, unsigned short* __restrict__ outQ)
{
    const int wgid = (int)blockIdx.x;          // 0..1023
    const int b = wgid >> 9, tft = wgid & 511;
    const int tfbase = tft * 128;

    const int tid = (int)threadIdx.x;
    const int wid = tid >> 6, lane = tid & 63;
    const int wr = wid >> 1, wc = wid & 1;
    const int lo16 = lane & 15, hi4 = lane >> 4;

    __shared__ unsigned short As[4 * 128 * 64];   // 64 KB panel
    __shared__ unsigned short Bs[128 * 64];       // 16 KB

    {
        const int a = lane & 7, cg = lane >> 3;
        const int rowb = wid * 32 + a * 4;
        const float* xb = x + (size_t)b * (C_ * T_ * F_) + tfbase + rowb;
        for (int cb = 0; cb < 256; cb += 64) {
            const int c0 = cb + cg * 8;
            float4 v[8];
#pragma unroll
            for (int g = 0; g < 8; ++g)
                v[g] = *(const float4*)(xb + (size_t)(c0 + g) * 65536);
            const int kc = cb >> 6;
#pragma unroll
            for (int j = 0; j < 4; ++j) {
                const int row = rowb + j;
                const int col8 = cg ^ (row & 7);
                float e0 = (&v[0].x)[j], e1 = (&v[1].x)[j], e2 = (&v[2].x)[j], e3 = (&v[3].x)[j];
                float e4 = (&v[4].x)[j], e5 = (&v[5].x)[j], e6 = (&v[6].x)[j], e7 = (&v[7].x)[j];
                ushort4 p0 = pack4(e0, e1, e2, e3);
                ushort4 p1 = pack4(e4, e5, e6, e7);
                *(ushort4*)&As[kc * 8192 + row * 64 + col8 * 8]     = p0;
                *(ushort4*)&As[kc * 8192 + row * 64 + col8 * 8 + 4] = p1;
            }
        }
    }

    const int srow = lane >> 3;
    const int scol = ((lane & 7) ^ srow) * 8;
    const int tf0 = tfbase + wr * 64;

    const int krot = wgid & 3;
    int nrot = wgid % 6;

    __syncthreads();

    for (int ntl_i = 0; ntl_i < 6; ++ntl_i) {
        int ntl = ntl_i + nrot; if (ntl >= 6) ntl -= 6;
        const int nbase = ntl * 128;
        const unsigned short* brow = Wall + (size_t)nbase * 256;
        f32x4 acc[4][4] = {};

        for (int kc_i = 0; kc_i < 4; ++kc_i) {
            const int kc = (kc_i + krot) & 3;
#pragma unroll
            for (int i = 0; i < 4; ++i) {
                const int rb = wid * 32 + i * 8;
                gload_lds16(brow + (size_t)(rb + srow) * 256 + kc * 64 + scol,
                            &Bs[rb * 64]);
            }
            __syncthreads();
#pragma unroll
            for (int kk = 0; kk < 2; ++kk) {
                const int hc = (kk * 32 + hi4 * 8) ^ ((lane & 7) << 3);
                bf16x8 a[4], bb[4];
#pragma unroll
                for (int mi = 0; mi < 4; ++mi)
                    a[mi] = *(const bf16x8*)&As[kc * 8192 + (wr * 64 + mi * 16 + lo16) * 64 + hc];
#pragma unroll
                for (int nj = 0; nj < 4; ++nj)
                    bb[nj] = *(const bf16x8*)&Bs[(wc * 64 + nj * 16 + lo16) * 64 + hc];
#pragma unroll
                for (int mi = 0; mi < 4; ++mi)
#pragma unroll
                    for (int nj = 0; nj < 4; ++nj)
                        mfma16(acc[mi][nj], a[mi], bb[nj]);
            }
            __syncthreads();
        }

        asm volatile("s_nop 7\n\ts_nop 7" ::: "memory");
#pragma unroll
        for (int nj = 0; nj < 4; ++nj) {
            const int r_col = nbase + wc * 64 + nj * 16 + lo16;
            const int projl = r_col >> 8;
            const int rr = r_col & 255;
            const int mrow = (rr >> 6) * 2 + b;
            const int h = rr & 63;
            const float bv = bias_all[r_col];
            unsigned short* dst0 = outQ + (size_t)projl * 33554432
                                 + (size_t)mrow * (T_ * E_) + h * 64;
#pragma unroll
            for (int mi = 0; mi < 4; ++mi) {
                const int tf = tf0 + mi * 16 + hi4 * 4;
                const int t = tf >> 6, f = tf & 63;
                *(ushort4*)(dst0 + (size_t)t * E_ + f) =
                    pack4(acc[mi][nj][0] + bv, acc[mi][nj][1] + bv,
                          acc[mi][nj][2] + bv, acc[mi][nj][3] + bv);
            }
        }
        if (ntl_i < 5) __syncthreads();
    }
}

// ---------------------------------------------------------------------------
// K2: scores, MFMA NT GEMM, XCD-chunked 1-D grid (round-6 verified)
// ---------------------------------------------------------------------------
__global__ __launch_bounds__(256) void scores_mfma(
    const unsigned short* __restrict__ Q, const unsigned short* __restrict__ K,
    unsigned short* __restrict__ S)
{
    const int orig = (int)blockIdx.x;                     // 512 blocks
    const int wg = (orig & 7) * 64 + (orig >> 3);
    const int m = wg >> 6;
    const int rest = wg & 63;
    const int sbase = (rest & 7) * 128;
    const int tbase = (rest >> 3) * 128;
    const int tid = (int)threadIdx.x;
    const int wid = tid >> 6, lane = tid & 63;
    const int wr = wid >> 1, wc = wid & 1;
    const int lo16 = lane & 15, hi4 = lane >> 4;

    __shared__ unsigned short As[128 * 64];
    __shared__ unsigned short Bs[128 * 64];

    f32x4 acc[4][4] = {};

    const unsigned short* qrow = Q + ((size_t)m * T_ + tbase) * E_;
    const unsigned short* krow = K + ((size_t)m * T_ + sbase) * E_;

    const int srow = lane >> 3;
    const int scol = ((lane & 7) ^ srow) * 8;

    for (int eb = 0; eb < E_; eb += 64) {
#pragma unroll
        for (int i = 0; i < 4; ++i) {
            const int rb = wid * 32 + i * 8;
            gload_lds16(qrow + (size_t)(rb + srow) * E_ + eb + scol, &As[rb * 64]);
            gload_lds16(krow + (size_t)(rb + srow) * E_ + eb + scol, &Bs[rb * 64]);
        }
        __syncthreads();
#pragma unroll
        for (int kk = 0; kk < 2; ++kk) {
            const int hc = (kk * 32 + hi4 * 8) ^ ((lane & 7) << 3);
            bf16x8 a[4], bb[4];
#pragma unroll
            for (int mi = 0; mi < 4; ++mi)
                a[mi] = *(const bf16x8*)&As[(wr * 64 + mi * 16 + lo16) * 64 + hc];
#pragma unroll
            for (int nj = 0; nj < 4; ++nj)
                bb[nj] = *(const bf16x8*)&Bs[(wc * 64 + nj * 16 + lo16) * 64 + hc];
#pragma unroll
            for (int mi = 0; mi < 4; ++mi)
#pragma unroll
                for (int nj = 0; nj < 4; ++nj)
                    mfma16(acc[mi][nj], a[mi], bb[nj]);
        }
        __syncthreads();
    }

    asm volatile("s_nop 7\n\ts_nop 7" ::: "memory");
#pragma unroll
    for (int mi = 0; mi < 4; ++mi)
#pragma unroll
        for (int r = 0; r < 4; ++r) {
            int trow = tbase + wr * 64 + mi * 16 + hi4 * 4 + r;
            unsigned short* sp = S + ((size_t)m * T_ + trow) * T_ + sbase + wc * 64 + lo16;
#pragma unroll
            for (int nj = 0; nj < 4; ++nj)
                sp[nj * 16] = bf16_rne(acc[mi][nj][r] * SCALE_);
        }
}

// ---------------------------------------------------------------------------
// K3: row softmax, one row per wave (round-12 verified)
// ---------------------------------------------------------------------------
__global__ __launch_bounds__(256) void softmax_kernel(
    const unsigned short* __restrict__ S, unsigned short* __restrict__ A)
{
    const int tid = (int)threadIdx.x;
    const int wid = tid >> 6, lane = tid & 63;
    const size_t rowoff = ((size_t)blockIdx.x * 4 + wid) * 1024;   // 2048 blocks

    const size_t off = rowoff + lane * 16;
    bf16x8 u0 = *(const bf16x8*)(S + off);
    bf16x8 u1 = *(const bf16x8*)(S + off + 8);

    float v[16];
#pragma unroll
    for (int i = 0; i < 8; ++i) {
        v[i]     = bf2f((unsigned short)u0[i]);
        v[i + 8] = bf2f((unsigned short)u1[i]);
    }

    float mx = v[0];
#pragma unroll
    for (int i = 1; i < 16; ++i) mx = fmaxf(mx, v[i]);
#pragma unroll
    for (int off2 = 32; off2 > 0; off2 >>= 1) mx = fmaxf(mx, __shfl_xor(mx, off2));

    float sm = 0.f;
#pragma unroll
    for (int i = 0; i < 16; ++i) { v[i] = __expf(v[i] - mx); sm += v[i]; }
#pragma unroll
    for (int off2 = 32; off2 > 0; off2 >>= 1) sm += __shfl_xor(sm, off2);
    const float inv = 1.0f / sm;

    bf16x8 r0, r1;
#pragma unroll
    for (int i = 0; i < 8; ++i) {
        r0[i] = (short)bf16_rne(v[i] * inv);
        r1[i] = (short)bf16_rne(v[i + 8] * inv);
    }
    *(bf16x8*)(A + off)     = r0;
    *(bf16x8*)(A + off + 8) = r1;
}

// ---------------------------------------------------------------------------
// K3b: V transpose (verified; cheaper than in-kernel transpose per round 15)
// ---------------------------------------------------------------------------
__global__ __launch_bounds__(256) void vt_kernel(
    const unsigned short* __restrict__ V, unsigned short* __restrict__ Vt)
{
    const int m = blockIdx.z;
    const int d0 = blockIdx.x * 64;
    const int s0 = blockIdx.y * 64;
    const int tid = (int)threadIdx.x;
    __shared__ unsigned short ts[64][68];

    const unsigned short* vp = V + (size_t)m * T_ * E_;
#pragma unroll
    for (int it = 0; it < 4; ++it) {
        int idx = it * 256 + tid;
        int sl = idx >> 4, d4 = (idx & 15) * 4;
        *(ushort4*)&ts[sl][d4] = *(const ushort4*)&vp[(size_t)(s0 + sl) * E_ + d0 + d4];
    }
    __syncthreads();
    unsigned short* op = Vt + (size_t)m * E_ * T_;
    const int dl = tid >> 2, s16 = (tid & 3) * 16;
#pragma unroll
    for (int q = 0; q < 4; ++q) {
        int s4 = s16 + q * 4;
        ushort4 v = make_ushort4(ts[s4][dl], ts[s4+1][dl], ts[s4+2][dl], ts[s4+3][dl]);
        *(ushort4*)&op[(size_t)(d0 + dl) * T_ + s0 + s4] = v;
    }
}

// ---------------------------------------------------------------------------
// K4: PV, MFMA NT GEMM vs Vt, XCD-chunked 1-D grid (round-6 verified)
// ---------------------------------------------------------------------------
__global__ __launch_bounds__(256) void pv_mfma(
    const unsigned short* __restrict__ A, const unsigned short* __restrict__ Vt,
    unsigned short* __restrict__ G)
{
    const int orig = (int)blockIdx.x;                     // 2048 blocks
    const int wg = (orig & 7) * 256 + (orig >> 3);
    const int m = wg >> 8;
    const int rest = wg & 255;
    const int dbase = (rest & 31) * 128;
    const int tbase = (rest >> 5) * 128;
    const int nh = m >> 1, b = m & 1;
    const int tid = (int)threadIdx.x;
    const int wid = tid >> 6, lane = tid & 63;
    const int wr = wid >> 1, wc = wid & 1;
    const int lo16 = lane & 15, hi4 = lane >> 4;

    __shared__ unsigned short As[128 * 64];
    __shared__ unsigned short Bs[128 * 64];

    f32x4 acc[4][4] = {};

    const unsigned short* arow = A  + ((size_t)m * T_ + tbase) * T_;
    const unsigned short* vrow = Vt + (size_t)m * E_ * T_ + (size_t)dbase * T_;

    const int srow = lane >> 3;
    const int scol = ((lane & 7) ^ srow) * 8;

    for (int sb = 0; sb < T_; sb += 64) {
#pragma unroll
        for (int i = 0; i < 4; ++i) {
            const int rb = wid * 32 + i * 8;
            gload_lds16(arow + (size_t)(rb + srow) * T_ + sb + scol, &As[rb * 64]);
            gload_lds16(vrow + (size_t)(rb + srow) * T_ + sb + scol, &Bs[rb * 64]);
        }
        __syncthreads();
#pragma unroll
        for (int kk = 0; kk < 2; ++kk) {
            const int hc = (kk * 32 + hi4 * 8) ^ ((lane & 7) << 3);
            bf16x8 a[4], bb[4];
#pragma unroll
            for (int mi = 0; mi < 4; ++mi)
                a[mi] = *(const bf16x8*)&As[(wr * 64 + mi * 16 + lo16) * 64 + hc];
#pragma unroll
            for (int nj = 0; nj < 4; ++nj)
                bb[nj] = *(const bf16x8*)&Bs[(wc * 64 + nj * 16 + lo16) * 64 + hc];
#pragma unroll
            for (int mi = 0; mi < 4; ++mi)
#pragma unroll
                for (int nj = 0; nj < 4; ++nj)
                    mfma16(acc[mi][nj], a[mi], bb[nj]);
        }
        __syncthreads();
    }

    asm volatile("s_nop 7\n\ts_nop 7" ::: "memory");
    const int cb   = nh * 64 + (dbase >> 6) + wc;
    const int t2lo = (tbase >> 6) + wr;
#pragma unroll
    for (int mi = 0; mi < 4; ++mi) {
        const int tl = mi * 16 + hi4 * 4;
#pragma unroll
        for (int nj = 0; nj < 4; ++nj) {
            const int d63 = nj * 16 + lo16;
            size_t addr = (((size_t)(b * 256 + cb)) * 1024 + d63 * 16 + t2lo) * 64 + tl;
            *(ushort4*)&G[addr] = pack4(acc[mi][nj][0], acc[mi][nj][1],
                                        acc[mi][nj][2], acc[mi][nj][3]);
        }
    }
}

// ---------------------------------------------------------------------------
// K5: out projection FUSED with G transpose (round-13 verified)
// ---------------------------------------------------------------------------
__global__ __launch_bounds__(256) void outproj_fused(
    const unsigned short* __restrict__ G, const unsigned short* __restrict__ Wpb,
    const float* __restrict__ bp, const float* __restrict__ x,
    float* __restrict__ out)
{
    const int tfbase = blockIdx.x * 128;
    const int obase  = blockIdx.y * 128;
    const int b      = blockIdx.z;
    const int tid = (int)threadIdx.x;
    const int wid = tid >> 6, lane = tid & 63;
    const int wr = wid >> 1, wc = wid & 1;
    const int lo16 = lane & 15, hi4 = lane >> 4;

    __shared__ unsigned short As[128 * 64];
    __shared__ unsigned short Bs[128 * 64];

    f32x4 acc[4][4] = {};

    const unsigned short* brow = Wpb + (size_t)obase * 256;

    const int srow = lane >> 3;
    const int scol = ((lane & 7) ^ srow) * 8;

    const int cg = tid >> 4;
    const int ag = tid & 15;

    for (int cb = 0; cb < 256; cb += 64) {
#pragma unroll
        for (int i = 0; i < 4; ++i) {
            const int rb = wid * 32 + i * 8;
            gload_lds16(brow + (size_t)(rb + srow) * 256 + cb + scol, &Bs[rb * 64]);
        }
        {
            const unsigned short* gb = G + ((size_t)(b * 256 + cb + cg * 4)) * 65536
                                     + tfbase + ag * 8;
            bf16x8 vv0 = *(const bf16x8*)(gb);
            bf16x8 vv1 = *(const bf16x8*)(gb + 65536);
            bf16x8 vv2 = *(const bf16x8*)(gb + 2 * 65536);
            bf16x8 vv3 = *(const bf16x8*)(gb + 3 * 65536);
#pragma unroll
            for (int j = 0; j < 8; ++j) {
                const int row = ag * 8 + j;
                const int phys = row * 64 + ((((cg >> 1) ^ (row & 7)) << 3) + (cg & 1) * 4);
                ushort4 w = make_ushort4((unsigned short)vv0[j], (unsigned short)vv1[j],
                                         (unsigned short)vv2[j], (unsigned short)vv3[j]);
                *(ushort4*)&As[phys] = w;
            }
        }
        __syncthreads();
#pragma unroll
        for (int kk = 0; kk < 2; ++kk) {
            const int hc = (kk * 32 + hi4 * 8) ^ ((lane & 7) << 3);
            bf16x8 a[4], bb[4];
#pragma unroll
            for (int mi = 0; mi < 4; ++mi)
                a[mi] = *(const bf16x8*)&As[(wr * 64 + mi * 16 + lo16) * 64 + hc];
#pragma unroll
            for (int nj = 0; nj < 4; ++nj)
                bb[nj] = *(const bf16x8*)&Bs[(wc * 64 + nj * 16 + lo16) * 64 + hc];
#pragma unroll
            for (int mi = 0; mi < 4; ++mi)
#pragma unroll
                for (int nj = 0; nj < 4; ++nj)
                    mfma16(acc[mi][nj], a[mi], bb[nj]);
        }
        __syncthreads();
    }

    asm volatile("s_nop 7\n\ts_nop 7" ::: "memory");
#pragma unroll
    for (int nj = 0; nj < 4; ++nj) {
        const int o = obase + wc * 64 + nj * 16 + lo16;
        const float bias = bp[o];
        const size_t rowb = ((size_t)(b * 256 + o)) * 65536;
#pragma unroll
        for (int mi = 0; mi < 4; ++mi) {
            const int tf = tfbase + wr * 64 + mi * 16 + hi4 * 4;
            float4 xv = *(const float4*)(x + rowb + tf);
            float4 r = make_float4(acc[mi][nj][0] + bias + xv.x,
                                   acc[mi][nj][1] + bias + xv.y,
                                   acc[mi][nj][2] + bias + xv.z,
                                   acc[mi][nj][3] + bias + xv.w);
            *(float4*)(out + rowb + tf) = r;
        }
    }
}

// ---------------------------------------------------------------------------
extern "C" void kernel_launch(void* const* d_in, const int* in_sizes, int n_in,
                              void* d_out, int out_size, void* d_ws, size_t ws_size,
                              hipStream_t stream) {
    const float* x  = (const float*)d_in[0];
    const float* Wq = (const float*)d_in[1];
    const float* bq = (const float*)d_in[2];
    const float* Wk = (const float*)d_in[3];
    const float* bk = (const float*)d_in[4];
    const float* Wv = (const float*)d_in[5];
    const float* bv = (const float*)d_in[6];
    const float* Wp = (const float*)d_in[7];
    const float* bp = (const float*)d_in[8];
    float* out = (float*)d_out;

    // workspace layout (peak ~235.4 MB) — round-13 aliasing
    char* ws = (char*)d_ws;
    unsigned short* Q    = (unsigned short*)(ws);                 // R0: Q -> G
    unsigned short* K    = (unsigned short*)(ws + 67108864);      // R1: K -> Vt
    unsigned short* V    = (unsigned short*)(ws + 134217728);     // R2: V
    unsigned short* S    = (unsigned short*)(ws + 201326592);     // 16 MB
    unsigned short* A    = (unsigned short*)(ws + 218103808);     // 16 MB
    unsigned short* Wall = (unsigned short*)(ws + 234881024);     // 393216 B
    float* bias_all      = (float*)(ws + 235274240);              // 3072 B
    unsigned short* Wpb  = (unsigned short*)(ws + 235277312);     // 131072 B
    unsigned short* Vt = K;    // written after scores (K dead)
    unsigned short* G  = Q;    // written after scores (Q dead)

    wconv_kernel<<<256, 256, 0, stream>>>(Wq, Wk, Wv, Wp, bq, bk, bv, Wall, Wpb, bias_all);
    qkv_one<<<1024, 256, 0, stream>>>(x, Wall, bias_all, Q);      // Q,K,V in one pass
    scores_mfma<<<512, 256, 0, stream>>>(Q, K, S);
    softmax_kernel<<<2048, 256, 0, stream>>>(S, A);
    vt_kernel<<<dim3(64, 16, M_), 256, 0, stream>>>(V, Vt);
    pv_mfma<<<2048, 256, 0, stream>>>(A, Vt, G);
    outproj_fused<<<dim3(512, 2, 2), 256, 0, stream>>>(G, Wpb, bp, x, out);
}